// Round 7
// baseline (13844.371 us; speedup 1.0000x reference)
//
#include <hip/hip_runtime.h>
#include <hip/hip_fp16.h>
#include <cstdint>

#define T_STEPS 1024
#define BATCH   128
#define DIM     256   // D
#define HID     256   // H
#define FF      128   // F
#define CHUNK   16

typedef _Float16 h2 __attribute__((ext_vector_type(2)));

// ws layout:
//   fp16 packed weights (units _Float16):
//     WgxP at 0      : [256/8][1024][8] = 262144 halfs (512 KB)  rows k<256 of Wg
//     WghP at 262144 : [256/8][1024][8] = 262144 halfs (512 KB)  rows k>=256
//     W1P  at 524288 : [4][H/8][F][8]   = 131072 halfs (256 KB)
//     W2P  at 655360 : [4][F/8][H][8]   = 131072 halfs (256 KB)
//   z2 exchange (uint, tag<<16 | fp16): [128 b][4 g][2 p][256 c] at byte 1572864 (1 MB)
#define WGXP_OFF 0
#define WGHP_OFF 262144
#define W1P_OFF  524288
#define W2P_OFF  655360
#define WS_HALFS 786432
#define EX_BYTE_OFF 1572864
#define EX_WORDS    262144
#define WS_SPLIT4_BYTES (EX_BYTE_OFF + EX_WORDS * 4)   // ~2.62 MB

__device__ __forceinline__ float sigmoidf_(float x) {
    return 1.0f / (1.0f + __expf(-x));
}
__device__ __forceinline__ float tanhf_(float x) {
    float e = __expf(2.0f * x);
    return 1.0f - 2.0f / (e + 1.0f);
}
__device__ __forceinline__ float fdot2_(h2 a, h2 b, float c) {
#if __has_builtin(__builtin_amdgcn_fdot2)
    return __builtin_amdgcn_fdot2(a, b, c, false);
#else
    return fmaf((float)a.x, (float)b.x, fmaf((float)a.y, (float)b.y, c));
#endif
}

union U4H { uint4 u; h2 h[4]; };
union HU  { unsigned short u; _Float16 h; };

// ---------------- weight convert + repack (fp32 -> fp16) ----------------
__global__ __launch_bounds__(256)
void convert_kernel(const float* __restrict__ Wg,
                    const float* __restrict__ W1,
                    const float* __restrict__ W2,
                    _Float16* __restrict__ ws)
{
    int i = blockIdx.x * 256 + threadIdx.x;
    if (i < 524288) {
        int k = i >> 10, c = i & 1023;
        if (k < 256) {
            ws[WGXP_OFF + (((size_t)(k >> 3) << 10) + c) * 8 + (k & 7)] = (_Float16)Wg[i];
        } else {
            int k2 = k - 256;
            ws[WGHP_OFF + (((size_t)(k2 >> 3) << 10) + c) * 8 + (k2 & 7)] = (_Float16)Wg[i];
        }
    } else if (i < 655360) {
        int j = i - 524288;           // W1 [4][H][F]
        int g = j >> 15, k = (j >> 7) & 255, f = j & 127;
        ws[W1P_OFF + (((size_t)((g << 5) + (k >> 3)) << 7) + f) * 8 + (k & 7)] = (_Float16)W1[j];
    } else if (i < 786432) {
        int j = i - 655360;           // W2 [4][F][H]
        int g = j >> 15, f = (j >> 8) & 127, h = j & 255;
        ws[W2P_OFF + (((size_t)((g << 4) + (f >> 3)) << 8) + h) * 8 + (f & 7)] = (_Float16)W2[j];
    }
}

__global__ __launch_bounds__(512)
void exinit_kernel(unsigned* __restrict__ ex) {
    int i = blockIdx.x * 512 + threadIdx.x;
    if (i < EX_WORDS) ex[i] = 0u;     // tag 0 != any s+1 >= 1
}

// ---------------- 4-way gate split, one batch per WG, 2 independent WGs/CU ----------
// blk in [0,512): g = (blk&255)>>6, b = (blk&63) + ((blk>>8)<<6).
// Pairs (blk, blk+256) co-reside on a CU: same gate (shared weight stream), different
// batch (independent barriers/spins). Exchange: tagged relaxed agent atomics, NO fences.
__global__ __launch_bounds__(512, 4)
void qlstm_split4g_kernel(const float* __restrict__ x,
                          const _Float16* __restrict__ ws,
                          unsigned* ex,
                          const float* __restrict__ bg,
                          const float* __restrict__ b1,
                          const float* __restrict__ b2,
                          float* __restrict__ out)
{
    const int blk = blockIdx.x;
    const int g   = (blk & 255) >> 6;               // gate 0..3
    const int b   = (blk & 63) + ((blk >> 8) << 6); // batch 0..127
    const int tid = threadIdx.x;

    __shared__ __align__(16) _Float16 xc[CHUNK * DIM];      // 8 KB
    __shared__ __align__(16) _Float16 zxc[CHUNK * 256];     // 8 KB (x-part of z + bg)
    __shared__ __align__(16) _Float16 ch2buf[256];          // h(t-1) fp16
    __shared__ __align__(16) _Float16 zh[256];              // z fp16
    __shared__ __align__(16) _Float16 h1h[128];             // FFN hidden fp16
    __shared__ float pbuf[512];                             // split-K partials (2 KB)
    __shared__ float bgs[256], b2s[256], b1s[128];

    if (tid < 256) {
        bgs[tid] = bg[(g << 8) + tid];
        b2s[tid] = b2[(g << 8) + tid];
        ch2buf[tid] = (_Float16)0.0f;
    }
    if (tid < 128) b1s[tid] = b1[(g << 7) + tid];
    float c_reg = 0.0f;                                     // cell state (tid<256: col=tid)
    __syncthreads();

    const uint4* __restrict__ wgxp = reinterpret_cast<const uint4*>(ws + WGXP_OFF);
    const uint4* __restrict__ wghp = reinterpret_cast<const uint4*>(ws + WGHP_OFF);
    const uint4* __restrict__ w1p  = reinterpret_cast<const uint4*>(ws + W1P_OFF);
    const uint4* __restrict__ w2p  = reinterpret_cast<const uint4*>(ws + W2P_OFF);
    const h2*  ch2 = reinterpret_cast<const h2*>(ch2buf);
    const U4H* xcv = reinterpret_cast<const U4H*>(xc);

    for (int t0 = 0; t0 < T_STEPS; t0 += CHUNK) {
        // ---- stage x chunk: 16 steps x 256 dims = 1024 float4, 2 per thread ----
        #pragma unroll
        for (int j = 0; j < 2; ++j) {
            int i4 = tid * 2 + j;
            int tl = i4 >> 6, d4 = i4 & 63;
            float4 v = reinterpret_cast<const float4*>(
                x + ((size_t)(t0 + tl) * BATCH + b) * DIM)[d4];
            int d0 = d4 << 2;
            xc[tl * 256 + d0 + 0] = (_Float16)v.x;
            xc[tl * 256 + d0 + 1] = (_Float16)v.y;
            xc[tl * 256 + d0 + 2] = (_Float16)v.z;
            xc[tl * 256 + d0 + 3] = (_Float16)v.w;
        }
        __syncthreads();

        // ---- chunk x-GEMM: zxc[tc][c] = bg[c] + sum_k xc[tc][k]*Wgx[k][g*256+c] ----
        {
            const int c = tid & 255, th = tid >> 8;     // th -> tc = th*8 + j
            float acc[8];
            #pragma unroll
            for (int j = 0; j < 8; ++j) acc[j] = bgs[c];
            for (int k8 = 0; k8 < 32; ++k8) {
                U4H w; w.u = wgxp[(k8 << 10) + (g << 8) + c];
                #pragma unroll
                for (int j = 0; j < 8; ++j) {
                    U4H xv; xv.u = xcv[(th * 8 + j) * 32 + k8].u;
                    acc[j] = fdot2_(xv.h[0], w.h[0], acc[j]);
                    acc[j] = fdot2_(xv.h[1], w.h[1], acc[j]);
                    acc[j] = fdot2_(xv.h[2], w.h[2], acc[j]);
                    acc[j] = fdot2_(xv.h[3], w.h[3], acc[j]);
                }
            }
            #pragma unroll
            for (int j = 0; j < 8; ++j)
                zxc[(th * 8 + j) * 256 + c] = (_Float16)acc[j];
        }
        __syncthreads();

        for (int tc = 0; tc < CHUNK; ++tc) {
            const int s = t0 + tc;

            // ---- p1: z[c] = zx[c] + sum_k h[k]*Wgh[k][g*256+c]; 2-way split-K ----
            {
                const int c = tid & 255, kh = tid >> 8;
                float acc = 0.0f;
                #pragma unroll
                for (int k8 = kh * 16; k8 < kh * 16 + 16; ++k8) {
                    U4H w; w.u = wghp[(k8 << 10) + (g << 8) + c];
                    acc = fdot2_(ch2[4 * k8 + 0], w.h[0], acc);
                    acc = fdot2_(ch2[4 * k8 + 1], w.h[1], acc);
                    acc = fdot2_(ch2[4 * k8 + 2], w.h[2], acc);
                    acc = fdot2_(ch2[4 * k8 + 3], w.h[3], acc);
                }
                pbuf[kh * 256 + c] = acc;
            }
            __syncthreads();
            if (tid < 256)
                zh[tid] = (_Float16)((float)zxc[tc * 256 + tid] + pbuf[tid] + pbuf[256 + tid]);
            __syncthreads();

            // ---- p2: h1[f] = relu(sum_k z[k]*W1[g][k][f] + b1); 4-way split-K ----
            {
                const int f = tid & 127, kq = tid >> 7;
                const h2* zp = reinterpret_cast<const h2*>(zh);
                float acc = 0.0f;
                #pragma unroll
                for (int k8 = kq * 8; k8 < kq * 8 + 8; ++k8) {
                    U4H w; w.u = w1p[(((g << 5) + k8) << 7) + f];
                    acc = fdot2_(zp[4 * k8 + 0], w.h[0], acc);
                    acc = fdot2_(zp[4 * k8 + 1], w.h[1], acc);
                    acc = fdot2_(zp[4 * k8 + 2], w.h[2], acc);
                    acc = fdot2_(zp[4 * k8 + 3], w.h[3], acc);
                }
                pbuf[kq * 128 + f] = acc;
            }
            __syncthreads();
            if (tid < 128)
                h1h[tid] = (_Float16)fmaxf(
                    b1s[tid] + pbuf[tid] + pbuf[128 + tid] + pbuf[256 + tid] + pbuf[384 + tid],
                    0.0f);
            __syncthreads();

            // ---- p3: z2[c] = sum_f h1[f]*W2[g][f][c] + b2; 2-way split-F ----
            {
                const int c = tid & 255, fh = tid >> 8;
                const h2* hp = reinterpret_cast<const h2*>(h1h);
                float acc = 0.0f;
                #pragma unroll
                for (int f8 = fh * 8; f8 < fh * 8 + 8; ++f8) {
                    U4H w; w.u = w2p[(((g << 4) + f8) << 8) + c];
                    acc = fdot2_(hp[4 * f8 + 0], w.h[0], acc);
                    acc = fdot2_(hp[4 * f8 + 1], w.h[1], acc);
                    acc = fdot2_(hp[4 * f8 + 2], w.h[2], acc);
                    acc = fdot2_(hp[4 * f8 + 3], w.h[3], acc);
                }
                pbuf[fh * 256 + c] = acc;
            }
            __syncthreads();

            // ---- publish z2 (tag s+1), then spin on all 4 gates, update c/h ----
            if (tid < 256) {
                float z2 = b2s[tid] + pbuf[tid] + pbuf[256 + tid];
                HU hu; hu.h = (_Float16)z2;
                unsigned word = ((unsigned)(s + 1) << 16) | (unsigned)hu.u;
                unsigned widx = (unsigned)(b * 2048 + g * 512 + ((s & 1) << 8) + tid);
                __hip_atomic_store(&ex[widx], word, __ATOMIC_RELAXED, __HIP_MEMORY_SCOPE_AGENT);

                const unsigned base = (unsigned)(b * 2048 + ((s & 1) << 8) + tid);
                const unsigned want = (unsigned)(s + 1) << 16;
                unsigned w0, w1, w2, w3;
                for (;;) {
                    w0 = __hip_atomic_load(&ex[base],        __ATOMIC_RELAXED, __HIP_MEMORY_SCOPE_AGENT);
                    w1 = __hip_atomic_load(&ex[base + 512],  __ATOMIC_RELAXED, __HIP_MEMORY_SCOPE_AGENT);
                    w2 = __hip_atomic_load(&ex[base + 1024], __ATOMIC_RELAXED, __HIP_MEMORY_SCOPE_AGENT);
                    w3 = __hip_atomic_load(&ex[base + 1536], __ATOMIC_RELAXED, __HIP_MEMORY_SCOPE_AGENT);
                    unsigned m = ((w0 ^ want) | (w1 ^ want) | (w2 ^ want) | (w3 ^ want)) & 0xFFFF0000u;
                    if (m == 0u) break;
                    __builtin_amdgcn_s_sleep(1);
                }
                HU hf, hi, hg, ho;
                hf.u = (unsigned short)(w0 & 0xFFFFu);
                hi.u = (unsigned short)(w1 & 0xFFFFu);
                hg.u = (unsigned short)(w2 & 0xFFFFu);
                ho.u = (unsigned short)(w3 & 0xFFFFu);
                float fg = sigmoidf_((float)hf.h);
                float ig = sigmoidf_((float)hi.h);
                float gg = tanhf_((float)hg.h);
                float og = sigmoidf_((float)ho.h);
                c_reg = fmaf(fg, c_reg, ig * gg);
                float hh = og * tanhf_(c_reg);
                ch2buf[tid] = (_Float16)hh;
                if (g == 0) {
                    out[((size_t)s * BATCH + b) * HID + tid] = hh;
                    if (s == T_STEPS - 1) {
                        const size_t TBH = (size_t)T_STEPS * BATCH * HID;
                        out[TBH + (size_t)b * HID + tid] = hh;
                        out[TBH + (size_t)BATCH * HID + (size_t)b * HID + tid] = c_reg;
                    }
                }
            }
            __syncthreads();
        }
    }
}

// ---------------- fallback: R4 chunk kernel (one WG per batch element) ----------------
__global__ __launch_bounds__(1024)
void qlstm_chunk_kernel(const float* __restrict__ x,
                        const _Float16* __restrict__ ws,
                        const float* __restrict__ bg,
                        const float* __restrict__ b1,
                        const float* __restrict__ b2,
                        float* __restrict__ out)
{
    const int b   = blockIdx.x;
    const int tid = threadIdx.x;

    __shared__ __align__(16) _Float16 xc[CHUNK * DIM];
    __shared__ __align__(16) _Float16 zxc[CHUNK * 1024];
    __shared__ __align__(16) _Float16 zh[1024];
    __shared__ __align__(16) _Float16 h1h[512];
    __shared__ __align__(16) _Float16 ch2buf[HID];
    __shared__ float z2buf[1024];
    __shared__ float cbuf[HID];
    __shared__ float hbuf[HID];

    const float rbg = bg[tid];
    const float rb1 = (tid < 512) ? b1[tid] : 0.0f;
    const float rb2 = b2[tid];

    if (tid < HID) { cbuf[tid] = 0.0f; hbuf[tid] = 0.0f; ch2buf[tid] = (_Float16)0.0f; }

    const uint4* __restrict__ wgxp = reinterpret_cast<const uint4*>(ws + WGXP_OFF);
    const uint4* __restrict__ wghp = reinterpret_cast<const uint4*>(ws + WGHP_OFF);
    const uint4* __restrict__ w1p  = reinterpret_cast<const uint4*>(ws + W1P_OFF);
    const uint4* __restrict__ w2p  = reinterpret_cast<const uint4*>(ws + W2P_OFF);
    const h2* ch2 = reinterpret_cast<const h2*>(ch2buf);
    const U4H* xcv = reinterpret_cast<const U4H*>(xc);

    for (int t0 = 0; t0 < T_STEPS; t0 += CHUNK) {
        #pragma unroll
        for (int j = 0; j < (CHUNK * DIM) / 1024; ++j) {
            int idx = tid + j * 1024;
            int tl = idx >> 8, d = idx & 255;
            xc[tl * DIM + d] = (_Float16)x[((size_t)(t0 + tl) * BATCH + b) * DIM + d];
        }
        __syncthreads();

        {
            float acc[CHUNK];
            #pragma unroll
            for (int tc = 0; tc < CHUNK; ++tc) acc[tc] = rbg;
            for (int k8 = 0; k8 < DIM / 8; ++k8) {
                U4H w; w.u = wgxp[(k8 << 10) + tid];
                #pragma unroll
                for (int tc = 0; tc < CHUNK; ++tc) {
                    U4H xv; xv.u = xcv[tc * (DIM / 8) + k8].u;
                    acc[tc] = fdot2_(xv.h[0], w.h[0], acc[tc]);
                    acc[tc] = fdot2_(xv.h[1], w.h[1], acc[tc]);
                    acc[tc] = fdot2_(xv.h[2], w.h[2], acc[tc]);
                    acc[tc] = fdot2_(xv.h[3], w.h[3], acc[tc]);
                }
            }
            #pragma unroll
            for (int tc = 0; tc < CHUNK; ++tc) zxc[tc * 1024 + tid] = (_Float16)acc[tc];
        }
        __syncthreads();

        for (int tc = 0; tc < CHUNK; ++tc) {
            {
                float acc = (float)zxc[tc * 1024 + tid];
                #pragma unroll 8
                for (int k8 = 0; k8 < HID / 8; ++k8) {
                    U4H w; w.u = wghp[(k8 << 10) + tid];
                    acc = fdot2_(ch2[4 * k8 + 0], w.h[0], acc);
                    acc = fdot2_(ch2[4 * k8 + 1], w.h[1], acc);
                    acc = fdot2_(ch2[4 * k8 + 2], w.h[2], acc);
                    acc = fdot2_(ch2[4 * k8 + 3], w.h[3], acc);
                }
                zh[tid] = (_Float16)acc;
            }
            __syncthreads();

            if (tid < 512) {
                const int g = tid >> 7, f = tid & 127;
                const h2* zp = reinterpret_cast<const h2*>(zh + (g << 8));
                float acc = rb1;
                #pragma unroll 8
                for (int k8 = 0; k8 < HID / 8; ++k8) {
                    U4H w; w.u = w1p[(((g << 5) + k8) << 7) + f];
                    acc = fdot2_(zp[4 * k8 + 0], w.h[0], acc);
                    acc = fdot2_(zp[4 * k8 + 1], w.h[1], acc);
                    acc = fdot2_(zp[4 * k8 + 2], w.h[2], acc);
                    acc = fdot2_(zp[4 * k8 + 3], w.h[3], acc);
                }
                h1h[tid] = (_Float16)fmaxf(acc, 0.0f);
            }
            __syncthreads();

            {
                const int g = tid >> 8, hcol = tid & 255;
                const h2* hp = reinterpret_cast<const h2*>(h1h + (g << 7));
                float acc = rb2;
                #pragma unroll 8
                for (int f8 = 0; f8 < FF / 8; ++f8) {
                    U4H w; w.u = w2p[(((g << 4) + f8) << 8) + hcol];
                    acc = fdot2_(hp[4 * f8 + 0], w.h[0], acc);
                    acc = fdot2_(hp[4 * f8 + 1], w.h[1], acc);
                    acc = fdot2_(hp[4 * f8 + 2], w.h[2], acc);
                    acc = fdot2_(hp[4 * f8 + 3], w.h[3], acc);
                }
                z2buf[tid] = acc;
            }
            __syncthreads();

            if (tid < HID) {
                float zf = z2buf[tid];
                float zi = z2buf[HID + tid];
                float zg = z2buf[2 * HID + tid];
                float zo = z2buf[3 * HID + tid];
                float fg = sigmoidf_(zf);
                float ig = sigmoidf_(zi);
                float gg = tanhf_(zg);
                float og = sigmoidf_(zo);
                float cc = fmaf(fg, cbuf[tid], ig * gg);
                float hh = og * tanhf_(cc);
                cbuf[tid] = cc;
                hbuf[tid] = hh;
                ch2buf[tid] = (_Float16)hh;
                out[((size_t)(t0 + tc) * BATCH + b) * HID + tid] = hh;
            }
            __syncthreads();
        }
    }

    if (tid < HID) {
        const size_t TBH = (size_t)T_STEPS * BATCH * HID;
        out[TBH + (size_t)b * HID + tid] = hbuf[tid];
        out[TBH + (size_t)BATCH * HID + (size_t)b * HID + tid] = cbuf[tid];
    }
}

extern "C" void kernel_launch(void* const* d_in, const int* in_sizes, int n_in,
                              void* d_out, int out_size, void* d_ws, size_t ws_size,
                              hipStream_t stream) {
    const float* x  = (const float*)d_in[0];
    const float* Wg = (const float*)d_in[1];
    const float* bg = (const float*)d_in[2];
    const float* W1 = (const float*)d_in[3];
    const float* b1 = (const float*)d_in[4];
    const float* W2 = (const float*)d_in[5];
    const float* b2 = (const float*)d_in[6];
    float* out = (float*)d_out;
    char* wsc = (char*)d_ws;

    if (ws_size >= (size_t)WS_SPLIT4_BYTES) {
        _Float16* ws = (_Float16*)wsc;
        unsigned* ex = (unsigned*)(wsc + EX_BYTE_OFF);
        convert_kernel<<<WS_HALFS / 256, 256, 0, stream>>>(Wg, W1, W2, ws);
        exinit_kernel<<<EX_WORDS / 512, 512, 0, stream>>>(ex);
        qlstm_split4g_kernel<<<512, 512, 0, stream>>>(x, ws, ex, bg, b1, b2, out);
    } else if (ws_size >= (size_t)WS_HALFS * sizeof(_Float16)) {
        _Float16* ws = (_Float16*)wsc;
        convert_kernel<<<WS_HALFS / 256, 256, 0, stream>>>(Wg, W1, W2, ws);
        qlstm_chunk_kernel<<<BATCH, 1024, 0, stream>>>(x, ws, bg, b1, b2, out);
    }
}

// Round 8
// 3841.069 us; speedup vs baseline: 3.6043x; 3.6043x over previous
//
#include <hip/hip_runtime.h>
#include <hip/hip_fp16.h>
#include <cstdint>

#define T_STEPS 1024
#define BATCH   128
#define DIM     256   // D
#define HID     256   // H
#define FF      128   // F
#define CHUNK   16

typedef _Float16 h2 __attribute__((ext_vector_type(2)));

// ws layout:
//   fp16 packed weights (units _Float16):
//     WgxP at 0      : [256/8][1024][8] = 262144 halfs (512 KB)  rows k<256 of Wg
//     WghP at 262144 : [256/8][1024][8] = 262144 halfs (512 KB)  rows k>=256
//     W1P  at 524288 : [4][H/8][F][8]   = 131072 halfs (256 KB)
//     W2P  at 655360 : [4][F/8][H][8]   = 131072 halfs (256 KB)
//   z2 exchange (uint, tag<<16 | fp16): [128 b][4 g][2 p][256 c] at byte 1572864 (1 MB)
#define WGXP_OFF 0
#define WGHP_OFF 262144
#define W1P_OFF  524288
#define W2P_OFF  655360
#define WS_HALFS 786432
#define EX_BYTE_OFF 1572864
#define EX_WORDS    262144
#define WS_SPLIT4_BYTES (EX_BYTE_OFF + EX_WORDS * 4)   // ~2.62 MB

__device__ __forceinline__ float sigmoidf_(float x) {
    return 1.0f / (1.0f + __expf(-x));
}
__device__ __forceinline__ float tanhf_(float x) {
    float e = __expf(2.0f * x);
    return 1.0f - 2.0f / (e + 1.0f);
}
__device__ __forceinline__ float fdot2_(h2 a, h2 b, float c) {
#if __has_builtin(__builtin_amdgcn_fdot2)
    return __builtin_amdgcn_fdot2(a, b, c, false);
#else
    return fmaf((float)a.x, (float)b.x, fmaf((float)a.y, (float)b.y, c));
#endif
}

union U4H { uint4 u; h2 h[4]; };
union HU  { unsigned short u; _Float16 h; };

// ---------------- weight convert + repack (fp32 -> fp16) ----------------
__global__ __launch_bounds__(256)
void convert_kernel(const float* __restrict__ Wg,
                    const float* __restrict__ W1,
                    const float* __restrict__ W2,
                    _Float16* __restrict__ ws)
{
    int i = blockIdx.x * 256 + threadIdx.x;
    if (i < 524288) {
        int k = i >> 10, c = i & 1023;
        if (k < 256) {
            ws[WGXP_OFF + (((size_t)(k >> 3) << 10) + c) * 8 + (k & 7)] = (_Float16)Wg[i];
        } else {
            int k2 = k - 256;
            ws[WGHP_OFF + (((size_t)(k2 >> 3) << 10) + c) * 8 + (k2 & 7)] = (_Float16)Wg[i];
        }
    } else if (i < 655360) {
        int j = i - 524288;           // W1 [4][H][F]
        int g = j >> 15, k = (j >> 7) & 255, f = j & 127;
        ws[W1P_OFF + (((size_t)((g << 5) + (k >> 3)) << 7) + f) * 8 + (k & 7)] = (_Float16)W1[j];
    } else if (i < 786432) {
        int j = i - 655360;           // W2 [4][F][H]
        int g = j >> 15, f = (j >> 8) & 127, h = j & 255;
        ws[W2P_OFF + (((size_t)((g << 4) + (f >> 3)) << 8) + h) * 8 + (f & 7)] = (_Float16)W2[j];
    }
}

__global__ __launch_bounds__(512)
void exinit_kernel(unsigned* __restrict__ ex) {
    int i = blockIdx.x * 512 + threadIdx.x;
    if (i < EX_WORDS) ex[i] = 0u;     // tag 0 != any s+1 >= 1
}

// ---------------- 4-way gate split, register-resident weights -------------------------
// blk = g*64 + bp; WG handles batches bp (A) and bp+64 (B); 512 threads, 1 WG per CU.
// All steady-state weights (Wgh/W1/W2 slices) live in 128 persistent VGPRs per thread.
// Exchange: R5-proven tagged relaxed agent atomics, double-buffered by parity, NO fences.
__global__ __launch_bounds__(512, 2)
void qlstm_split4r_kernel(const float* __restrict__ x,
                          const _Float16* __restrict__ ws,
                          unsigned* ex,
                          const float* __restrict__ bg,
                          const float* __restrict__ b1,
                          const float* __restrict__ b2,
                          float* __restrict__ out)
{
    const int blk = blockIdx.x;
    const int g   = blk >> 6;          // gate 0..3
    const int bp  = blk & 63;          // batch-pair base
    const int tid = threadIdx.x;

    __shared__ __align__(16) _Float16 xc[2 * CHUNK * DIM];      // 16 KB  x chunk (A,B)
    __shared__ __align__(16) _Float16 zxc[2 * CHUNK * 256];     // 16 KB  x-part of z + bg
    __shared__ __align__(16) _Float16 ch2buf[512];              // [2][256] h(t-1)
    __shared__ __align__(16) _Float16 zh[512];                  // [2][256] z
    __shared__ __align__(16) _Float16 h1h[256];                 // [2][128] FFN hidden
    __shared__ float pbuf[1024];                                // split-K partials (A|B)
    __shared__ float bgs[256], b2s[256], b1s[128];

    if (tid < 256) {
        bgs[tid] = bg[(g << 8) + tid];
        b2s[tid] = b2[(g << 8) + tid];
    }
    if (tid < 128) b1s[tid] = b1[(g << 7) + tid];
    ch2buf[tid] = (_Float16)0.0f;                               // 512 = [2][256]
    float c_reg = 0.0f;                                         // cell state for (bl,c)=tid

    const uint4* __restrict__ wgxp = reinterpret_cast<const uint4*>(ws + WGXP_OFF);
    const uint4* __restrict__ wghp = reinterpret_cast<const uint4*>(ws + WGHP_OFF);
    const uint4* __restrict__ w1p  = reinterpret_cast<const uint4*>(ws + W1P_OFF);
    const uint4* __restrict__ w2p  = reinterpret_cast<const uint4*>(ws + W2P_OFF);

    // per-phase thread roles (waves are 64-aligned -> role bits wave-uniform)
    const int cc   = tid & 255;               // p1/p3/x-gemm column
    const int kh16 = (tid >> 8) << 4;         // p1: split-K half * 16
    const int kq8  = ((tid >> 7) & 3) << 3;   // p2: split-K quarter * 8
    const int ffi  = tid & 127;               // p2 column
    const int fh8  = (tid >> 8) << 3;         // p3: split-F half * 8

    // ---- persistent weight registers: 16+8+8 = 32 uint4 = 128 VGPR ----
    uint4 wgh_r[16], w1_r[8], w2_r[8];
    #pragma unroll
    for (int j = 0; j < 16; ++j) wgh_r[j] = wghp[((kh16 + j) << 10) + (g << 8) + cc];
    #pragma unroll
    for (int j = 0; j < 8; ++j)  w1_r[j]  = w1p[(((g << 5) + kq8 + j) << 7) + ffi];
    #pragma unroll
    for (int j = 0; j < 8; ++j)  w2_r[j]  = w2p[(((g << 4) + fh8 + j) << 8) + cc];

    __syncthreads();

    for (int t0 = 0; t0 < T_STEPS; t0 += CHUNK) {
        // ---- stage x chunk: 2 batches x 16 steps x 256 dims = 2048 float4 ----
        #pragma unroll
        for (int j = 0; j < 4; ++j) {
            int i4 = j * 512 + tid;
            int bl = i4 >> 10, rem = i4 & 1023, tl = rem >> 6, d4 = rem & 63;
            float4 v = reinterpret_cast<const float4*>(
                x + ((size_t)(t0 + tl) * BATCH + bp + (bl << 6)) * DIM)[d4];
            int base = bl * 4096 + tl * 256 + (d4 << 2);
            xc[base + 0] = (_Float16)v.x;
            xc[base + 1] = (_Float16)v.y;
            xc[base + 2] = (_Float16)v.z;
            xc[base + 3] = (_Float16)v.w;
        }
        __syncthreads();

        // ---- chunk x-GEMM (streams Wgx slice once/chunk = ~8KB/step amortized) ----
        {
            const int th = tid >> 8;                       // tc block 0/1 -> tc = th*8+j
            const U4H* xcv = reinterpret_cast<const U4H*>(xc);   // [2][16][32]
            float acc[2][8];
            #pragma unroll
            for (int bl = 0; bl < 2; ++bl)
                #pragma unroll
                for (int j = 0; j < 8; ++j) acc[bl][j] = bgs[cc];
            for (int k8 = 0; k8 < 32; ++k8) {
                U4H w; w.u = wgxp[(k8 << 10) + (g << 8) + cc];
                #pragma unroll
                for (int bl = 0; bl < 2; ++bl) {
                    #pragma unroll
                    for (int j = 0; j < 8; ++j) {
                        U4H xv; xv.u = xcv[bl * 512 + (th * 8 + j) * 32 + k8].u;
                        acc[bl][j] = fdot2_(xv.h[0], w.h[0], acc[bl][j]);
                        acc[bl][j] = fdot2_(xv.h[1], w.h[1], acc[bl][j]);
                        acc[bl][j] = fdot2_(xv.h[2], w.h[2], acc[bl][j]);
                        acc[bl][j] = fdot2_(xv.h[3], w.h[3], acc[bl][j]);
                    }
                }
            }
            #pragma unroll
            for (int bl = 0; bl < 2; ++bl)
                #pragma unroll
                for (int j = 0; j < 8; ++j)
                    zxc[bl * 4096 + (th * 8 + j) * 256 + cc] = (_Float16)acc[bl][j];
        }
        __syncthreads();

        for (int tc = 0; tc < CHUNK; ++tc) {
            const int s = t0 + tc;

            // ---- p1: z partials from register Wgh; h via uniform b128 LDS reads ----
            {
                const uint4* hA4 = reinterpret_cast<const uint4*>(ch2buf);
                const uint4* hB4 = reinterpret_cast<const uint4*>(ch2buf + 256);
                float aA = 0.0f, aB = 0.0f;
                #pragma unroll
                for (int j = 0; j < 16; ++j) {
                    const int k8 = kh16 + j;
                    U4H w;  w.u  = wgh_r[j];
                    U4H ha; ha.u = hA4[k8];
                    U4H hb; hb.u = hB4[k8];
                    aA = fdot2_(ha.h[0], w.h[0], aA);
                    aA = fdot2_(ha.h[1], w.h[1], aA);
                    aA = fdot2_(ha.h[2], w.h[2], aA);
                    aA = fdot2_(ha.h[3], w.h[3], aA);
                    aB = fdot2_(hb.h[0], w.h[0], aB);
                    aB = fdot2_(hb.h[1], w.h[1], aB);
                    aB = fdot2_(hb.h[2], w.h[2], aB);
                    aB = fdot2_(hb.h[3], w.h[3], aB);
                }
                pbuf[tid] = aA;
                pbuf[512 + tid] = aB;
            }
            __syncthreads();
            {   // combine1: z = zx + partials; (bl,c) = tid
                const int bl = tid >> 8, c = tid & 255;
                float z = (float)zxc[bl * 4096 + tc * 256 + c]
                        + pbuf[bl * 512 + c] + pbuf[bl * 512 + 256 + c];
                zh[bl * 256 + c] = (_Float16)z;
            }
            __syncthreads();

            // ---- p2: h1 partials from register W1 ----
            {
                const uint4* zA4 = reinterpret_cast<const uint4*>(zh);
                const uint4* zB4 = reinterpret_cast<const uint4*>(zh + 256);
                float aA = 0.0f, aB = 0.0f;
                #pragma unroll
                for (int j = 0; j < 8; ++j) {
                    const int k8 = kq8 + j;
                    U4H w;  w.u  = w1_r[j];
                    U4H za; za.u = zA4[k8];
                    U4H zb; zb.u = zB4[k8];
                    aA = fdot2_(za.h[0], w.h[0], aA);
                    aA = fdot2_(za.h[1], w.h[1], aA);
                    aA = fdot2_(za.h[2], w.h[2], aA);
                    aA = fdot2_(za.h[3], w.h[3], aA);
                    aB = fdot2_(zb.h[0], w.h[0], aB);
                    aB = fdot2_(zb.h[1], w.h[1], aB);
                    aB = fdot2_(zb.h[2], w.h[2], aB);
                    aB = fdot2_(zb.h[3], w.h[3], aB);
                }
                pbuf[tid] = aA;
                pbuf[512 + tid] = aB;
            }
            __syncthreads();
            if (tid < 256) {   // combine2: (bl,f)
                const int bl = tid >> 7, f = tid & 127;
                float v = b1s[f] + pbuf[bl * 512 + f] + pbuf[bl * 512 + 128 + f]
                                 + pbuf[bl * 512 + 256 + f] + pbuf[bl * 512 + 384 + f];
                h1h[bl * 128 + f] = (_Float16)fmaxf(v, 0.0f);
            }
            __syncthreads();

            // ---- p3: z2 partials from register W2 ----
            {
                const uint4* pA4 = reinterpret_cast<const uint4*>(h1h);
                const uint4* pB4 = reinterpret_cast<const uint4*>(h1h + 128);
                float aA = 0.0f, aB = 0.0f;
                #pragma unroll
                for (int j = 0; j < 8; ++j) {
                    const int f8 = fh8 + j;
                    U4H w;  w.u  = w2_r[j];
                    U4H ha; ha.u = pA4[f8];
                    U4H hb; hb.u = pB4[f8];
                    aA = fdot2_(ha.h[0], w.h[0], aA);
                    aA = fdot2_(ha.h[1], w.h[1], aA);
                    aA = fdot2_(ha.h[2], w.h[2], aA);
                    aA = fdot2_(ha.h[3], w.h[3], aA);
                    aB = fdot2_(hb.h[0], w.h[0], aB);
                    aB = fdot2_(hb.h[1], w.h[1], aB);
                    aB = fdot2_(hb.h[2], w.h[2], aB);
                    aB = fdot2_(hb.h[3], w.h[3], aB);
                }
                pbuf[tid] = aA;
                pbuf[512 + tid] = aB;
            }
            __syncthreads();

            // ---- combine3 + publish (tag s+1) + spin on 4 gates + update ----
            {
                const int bl = tid >> 8, c = tid & 255;
                const int b  = bp + (bl << 6);
                float z2 = b2s[c] + pbuf[bl * 512 + c] + pbuf[bl * 512 + 256 + c];
                HU hu; hu.h = (_Float16)z2;
                unsigned word = ((unsigned)(s + 1) << 16) | (unsigned)hu.u;
                unsigned widx = (unsigned)(b * 2048 + g * 512 + ((s & 1) << 8) + c);
                __hip_atomic_store(&ex[widx], word, __ATOMIC_RELAXED, __HIP_MEMORY_SCOPE_AGENT);

                const unsigned base = (unsigned)(b * 2048 + ((s & 1) << 8) + c);
                const unsigned want = (unsigned)(s + 1) << 16;
                unsigned w0, w1, w2, w3;
                for (;;) {
                    w0 = __hip_atomic_load(&ex[base],        __ATOMIC_RELAXED, __HIP_MEMORY_SCOPE_AGENT);
                    w1 = __hip_atomic_load(&ex[base + 512],  __ATOMIC_RELAXED, __HIP_MEMORY_SCOPE_AGENT);
                    w2 = __hip_atomic_load(&ex[base + 1024], __ATOMIC_RELAXED, __HIP_MEMORY_SCOPE_AGENT);
                    w3 = __hip_atomic_load(&ex[base + 1536], __ATOMIC_RELAXED, __HIP_MEMORY_SCOPE_AGENT);
                    unsigned m = ((w0 ^ want) | (w1 ^ want) | (w2 ^ want) | (w3 ^ want)) & 0xFFFF0000u;
                    if (m == 0u) break;
                    __builtin_amdgcn_s_sleep(1);
                }
                HU hf, hi, hg, ho;
                hf.u = (unsigned short)(w0 & 0xFFFFu);
                hi.u = (unsigned short)(w1 & 0xFFFFu);
                hg.u = (unsigned short)(w2 & 0xFFFFu);
                ho.u = (unsigned short)(w3 & 0xFFFFu);
                float fg = sigmoidf_((float)hf.h);
                float ig = sigmoidf_((float)hi.h);
                float gg = tanhf_((float)hg.h);
                float og = sigmoidf_((float)ho.h);
                c_reg = fmaf(fg, c_reg, ig * gg);
                float hh = og * tanhf_(c_reg);
                ch2buf[bl * 256 + c] = (_Float16)hh;
                if (g == 0) {
                    out[((size_t)s * BATCH + b) * HID + c] = hh;
                    if (s == T_STEPS - 1) {
                        const size_t TBH = (size_t)T_STEPS * BATCH * HID;
                        out[TBH + (size_t)b * HID + c] = hh;
                        out[TBH + (size_t)BATCH * HID + (size_t)b * HID + c] = c_reg;
                    }
                }
            }
            __syncthreads();
        }
    }
}

// ---------------- fallback: R4 chunk kernel (one WG per batch element) ----------------
__global__ __launch_bounds__(1024)
void qlstm_chunk_kernel(const float* __restrict__ x,
                        const _Float16* __restrict__ ws,
                        const float* __restrict__ bg,
                        const float* __restrict__ b1,
                        const float* __restrict__ b2,
                        float* __restrict__ out)
{
    const int b   = blockIdx.x;
    const int tid = threadIdx.x;

    __shared__ __align__(16) _Float16 xc[CHUNK * DIM];
    __shared__ __align__(16) _Float16 zxc[CHUNK * 1024];
    __shared__ __align__(16) _Float16 zh[1024];
    __shared__ __align__(16) _Float16 h1h[512];
    __shared__ __align__(16) _Float16 ch2buf[HID];
    __shared__ float z2buf[1024];
    __shared__ float cbuf[HID];
    __shared__ float hbuf[HID];

    const float rbg = bg[tid];
    const float rb1 = (tid < 512) ? b1[tid] : 0.0f;
    const float rb2 = b2[tid];

    if (tid < HID) { cbuf[tid] = 0.0f; hbuf[tid] = 0.0f; ch2buf[tid] = (_Float16)0.0f; }

    const uint4* __restrict__ wgxp = reinterpret_cast<const uint4*>(ws + WGXP_OFF);
    const uint4* __restrict__ wghp = reinterpret_cast<const uint4*>(ws + WGHP_OFF);
    const uint4* __restrict__ w1p  = reinterpret_cast<const uint4*>(ws + W1P_OFF);
    const uint4* __restrict__ w2p  = reinterpret_cast<const uint4*>(ws + W2P_OFF);
    const h2* ch2 = reinterpret_cast<const h2*>(ch2buf);
    const U4H* xcv = reinterpret_cast<const U4H*>(xc);

    for (int t0 = 0; t0 < T_STEPS; t0 += CHUNK) {
        #pragma unroll
        for (int j = 0; j < (CHUNK * DIM) / 1024; ++j) {
            int idx = tid + j * 1024;
            int tl = idx >> 8, d = idx & 255;
            xc[tl * DIM + d] = (_Float16)x[((size_t)(t0 + tl) * BATCH + b) * DIM + d];
        }
        __syncthreads();

        {
            float acc[CHUNK];
            #pragma unroll
            for (int tc = 0; tc < CHUNK; ++tc) acc[tc] = rbg;
            for (int k8 = 0; k8 < DIM / 8; ++k8) {
                U4H w; w.u = wgxp[(k8 << 10) + tid];
                #pragma unroll
                for (int tc = 0; tc < CHUNK; ++tc) {
                    U4H xv; xv.u = xcv[tc * (DIM / 8) + k8].u;
                    acc[tc] = fdot2_(xv.h[0], w.h[0], acc[tc]);
                    acc[tc] = fdot2_(xv.h[1], w.h[1], acc[tc]);
                    acc[tc] = fdot2_(xv.h[2], w.h[2], acc[tc]);
                    acc[tc] = fdot2_(xv.h[3], w.h[3], acc[tc]);
                }
            }
            #pragma unroll
            for (int tc = 0; tc < CHUNK; ++tc) zxc[tc * 1024 + tid] = (_Float16)acc[tc];
        }
        __syncthreads();

        for (int tc = 0; tc < CHUNK; ++tc) {
            {
                float acc = (float)zxc[tc * 1024 + tid];
                #pragma unroll 8
                for (int k8 = 0; k8 < HID / 8; ++k8) {
                    U4H w; w.u = wghp[(k8 << 10) + tid];
                    acc = fdot2_(ch2[4 * k8 + 0], w.h[0], acc);
                    acc = fdot2_(ch2[4 * k8 + 1], w.h[1], acc);
                    acc = fdot2_(ch2[4 * k8 + 2], w.h[2], acc);
                    acc = fdot2_(ch2[4 * k8 + 3], w.h[3], acc);
                }
                zh[tid] = (_Float16)acc;
            }
            __syncthreads();

            if (tid < 512) {
                const int g = tid >> 7, f = tid & 127;
                const h2* zp = reinterpret_cast<const h2*>(zh + (g << 8));
                float acc = rb1;
                #pragma unroll 8
                for (int k8 = 0; k8 < HID / 8; ++k8) {
                    U4H w; w.u = w1p[(((g << 5) + k8) << 7) + f];
                    acc = fdot2_(zp[4 * k8 + 0], w.h[0], acc);
                    acc = fdot2_(zp[4 * k8 + 1], w.h[1], acc);
                    acc = fdot2_(zp[4 * k8 + 2], w.h[2], acc);
                    acc = fdot2_(zp[4 * k8 + 3], w.h[3], acc);
                }
                h1h[tid] = (_Float16)fmaxf(acc, 0.0f);
            }
            __syncthreads();

            {
                const int g = tid >> 8, hcol = tid & 255;
                const h2* hp = reinterpret_cast<const h2*>(h1h + (g << 7));
                float acc = rb2;
                #pragma unroll 8
                for (int f8 = 0; f8 < FF / 8; ++f8) {
                    U4H w; w.u = w2p[(((g << 4) + f8) << 8) + hcol];
                    acc = fdot2_(hp[4 * f8 + 0], w.h[0], acc);
                    acc = fdot2_(hp[4 * f8 + 1], w.h[1], acc);
                    acc = fdot2_(hp[4 * f8 + 2], w.h[2], acc);
                    acc = fdot2_(hp[4 * f8 + 3], w.h[3], acc);
                }
                z2buf[tid] = acc;
            }
            __syncthreads();

            if (tid < HID) {
                float zf = z2buf[tid];
                float zi = z2buf[HID + tid];
                float zg = z2buf[2 * HID + tid];
                float zo = z2buf[3 * HID + tid];
                float fg = sigmoidf_(zf);
                float ig = sigmoidf_(zi);
                float gg = tanhf_(zg);
                float og = sigmoidf_(zo);
                float cc = fmaf(fg, cbuf[tid], ig * gg);
                float hh = og * tanhf_(cc);
                cbuf[tid] = cc;
                hbuf[tid] = hh;
                ch2buf[tid] = (_Float16)hh;
                out[((size_t)(t0 + tc) * BATCH + b) * HID + tid] = hh;
            }
            __syncthreads();
        }
    }

    if (tid < HID) {
        const size_t TBH = (size_t)T_STEPS * BATCH * HID;
        out[TBH + (size_t)b * HID + tid] = hbuf[tid];
        out[TBH + (size_t)BATCH * HID + (size_t)b * HID + tid] = cbuf[tid];
    }
}

extern "C" void kernel_launch(void* const* d_in, const int* in_sizes, int n_in,
                              void* d_out, int out_size, void* d_ws, size_t ws_size,
                              hipStream_t stream) {
    const float* x  = (const float*)d_in[0];
    const float* Wg = (const float*)d_in[1];
    const float* bg = (const float*)d_in[2];
    const float* W1 = (const float*)d_in[3];
    const float* b1 = (const float*)d_in[4];
    const float* W2 = (const float*)d_in[5];
    const float* b2 = (const float*)d_in[6];
    float* out = (float*)d_out;
    char* wsc = (char*)d_ws;

    if (ws_size >= (size_t)WS_SPLIT4_BYTES) {
        _Float16* ws = (_Float16*)wsc;
        unsigned* ex = (unsigned*)(wsc + EX_BYTE_OFF);
        convert_kernel<<<WS_HALFS / 256, 256, 0, stream>>>(Wg, W1, W2, ws);
        exinit_kernel<<<EX_WORDS / 512, 512, 0, stream>>>(ex);
        qlstm_split4r_kernel<<<256, 512, 0, stream>>>(x, ws, ex, bg, b1, b2, out);
    } else if (ws_size >= (size_t)WS_HALFS * sizeof(_Float16)) {
        _Float16* ws = (_Float16*)wsc;
        convert_kernel<<<WS_HALFS / 256, 256, 0, stream>>>(Wg, W1, W2, ws);
        qlstm_chunk_kernel<<<BATCH, 1024, 0, stream>>>(x, ws, bg, b1, b2, out);
    }
}

// Round 9
// 3758.452 us; speedup vs baseline: 3.6835x; 1.0220x over previous
//
#include <hip/hip_runtime.h>
#include <hip/hip_fp16.h>
#include <cstdint>

#define T_STEPS 1024
#define BATCH   128
#define DIM     256   // D
#define HID     256   // H
#define FF      128   // F
#define CHUNK   16

typedef _Float16 h2 __attribute__((ext_vector_type(2)));

// ws layout:
//   fp16 packed weights (units _Float16):
//     WgxP at 0      : [256/8][1024][8] = 262144 halfs (512 KB)  rows k<256 of Wg
//     WghP at 262144 : [256/8][1024][8] = 262144 halfs (512 KB)  rows k>=256
//     W1P  at 524288 : [4][H/8][F][8]   = 131072 halfs (256 KB)
//     W2P  at 655360 : [4][F/8][H][8]   = 131072 halfs (256 KB)
//   z2 exchange (uint, tag<<16 | fp16): [128 b][4 g][2 p][256 c] at byte 1572864 (1 MB)
#define WGXP_OFF 0
#define WGHP_OFF 262144
#define W1P_OFF  524288
#define W2P_OFF  655360
#define WS_HALFS 786432
#define EX_BYTE_OFF 1572864
#define EX_WORDS    262144
#define WS_SPLIT4_BYTES (EX_BYTE_OFF + EX_WORDS * 4)   // ~2.62 MB

// value barrier: forces v to live in VGPRs; compiler cannot re-materialize the load
#define KEEPU4(v) asm volatile("" : "+v"((v).x), "+v"((v).y), "+v"((v).z), "+v"((v).w))

__device__ __forceinline__ float sigmoidf_(float x) {
    return 1.0f / (1.0f + __expf(-x));
}
__device__ __forceinline__ float tanhf_(float x) {
    float e = __expf(2.0f * x);
    return 1.0f - 2.0f / (e + 1.0f);
}
__device__ __forceinline__ float fdot2_(h2 a, h2 b, float c) {
#if __has_builtin(__builtin_amdgcn_fdot2)
    return __builtin_amdgcn_fdot2(a, b, c, false);
#else
    return fmaf((float)a.x, (float)b.x, fmaf((float)a.y, (float)b.y, c));
#endif
}

union U4H { uint4 u; h2 h[4]; };
union HU  { unsigned short u; _Float16 h; };

// ---------------- weight convert + repack (fp32 -> fp16) ----------------
__global__ __launch_bounds__(256)
void convert_kernel(const float* __restrict__ Wg,
                    const float* __restrict__ W1,
                    const float* __restrict__ W2,
                    _Float16* __restrict__ ws)
{
    int i = blockIdx.x * 256 + threadIdx.x;
    if (i < 524288) {
        int k = i >> 10, c = i & 1023;
        if (k < 256) {
            ws[WGXP_OFF + (((size_t)(k >> 3) << 10) + c) * 8 + (k & 7)] = (_Float16)Wg[i];
        } else {
            int k2 = k - 256;
            ws[WGHP_OFF + (((size_t)(k2 >> 3) << 10) + c) * 8 + (k2 & 7)] = (_Float16)Wg[i];
        }
    } else if (i < 655360) {
        int j = i - 524288;           // W1 [4][H][F]
        int g = j >> 15, k = (j >> 7) & 255, f = j & 127;
        ws[W1P_OFF + (((size_t)((g << 5) + (k >> 3)) << 7) + f) * 8 + (k & 7)] = (_Float16)W1[j];
    } else if (i < 786432) {
        int j = i - 655360;           // W2 [4][F][H]
        int g = j >> 15, f = (j >> 8) & 127, h = j & 255;
        ws[W2P_OFF + (((size_t)((g << 4) + (f >> 3)) << 8) + h) * 8 + (f & 7)] = (_Float16)W2[j];
    }
}

__global__ __launch_bounds__(512)
void exinit_kernel(unsigned* __restrict__ ex) {
    int i = blockIdx.x * 512 + threadIdx.x;
    if (i < EX_WORDS) ex[i] = 0u;     // tag 0 != any s+1 >= 1
}

// ---------------- 4-way gate split, register-resident weights (forced) ----------------
// blk = g*64 + bp; WG handles batches bp (A) and bp+64 (B); 512 threads, 1 WG per CU.
// Wgh/W1/W2 slices pinned in 128 VGPRs via asm value barriers (R8 lesson: without the
// barrier the compiler rematerializes the loads in-loop = 256 KB/step/CU L2 stream).
// Exchange: R5-proven tagged relaxed agent atomics, double-buffered by parity, NO fences.
__global__ __launch_bounds__(512, 2)
void qlstm_split4r_kernel(const float* __restrict__ x,
                          const _Float16* __restrict__ ws,
                          unsigned* ex,
                          const float* __restrict__ bg,
                          const float* __restrict__ b1,
                          const float* __restrict__ b2,
                          float* __restrict__ out)
{
    const int blk = blockIdx.x;
    const int g   = blk >> 6;          // gate 0..3
    const int bp  = blk & 63;          // batch-pair base
    const int tid = threadIdx.x;

    __shared__ __align__(16) _Float16 xc[2 * CHUNK * DIM];      // 16 KB  x chunk (A,B)
    __shared__ __align__(16) _Float16 zxc[2 * CHUNK * 256];     // 16 KB  x-part of z + bg
    __shared__ __align__(16) _Float16 ch2buf[512];              // [2][256] h(t-1)
    __shared__ __align__(16) _Float16 zh[512];                  // [2][256] z
    __shared__ __align__(16) _Float16 h1h[256];                 // [2][128] FFN hidden
    __shared__ float pbuf[1024];                                // split-K partials (A|B)
    __shared__ float bgs[256], b2s[256], b1s[128];

    if (tid < 256) {
        bgs[tid] = bg[(g << 8) + tid];
        b2s[tid] = b2[(g << 8) + tid];
    }
    if (tid < 128) b1s[tid] = b1[(g << 7) + tid];
    ch2buf[tid] = (_Float16)0.0f;                               // 512 = [2][256]
    float c_reg = 0.0f;                                         // cell state for (bl,c)=tid

    const uint4* __restrict__ wgxp = reinterpret_cast<const uint4*>(ws + WGXP_OFF);
    const uint4* __restrict__ wghp = reinterpret_cast<const uint4*>(ws + WGHP_OFF);
    const uint4* __restrict__ w1p  = reinterpret_cast<const uint4*>(ws + W1P_OFF);
    const uint4* __restrict__ w2p  = reinterpret_cast<const uint4*>(ws + W2P_OFF);

    // per-phase thread roles (waves are 64-aligned -> role bits wave-uniform)
    const int cc   = tid & 255;               // p1/p3/x-gemm column
    const int kh16 = (tid >> 8) << 4;         // p1: split-K half * 16
    const int kq8  = ((tid >> 7) & 3) << 3;   // p2: split-K quarter * 8
    const int ffi  = tid & 127;               // p2 column
    const int fh8  = (tid >> 8) << 3;         // p3: split-F half * 8

    // ---- persistent weight registers: 16+8+8 = 32 uint4 = 128 VGPR, PINNED ----
    uint4 wgh_r[16], w1_r[8], w2_r[8];
    #pragma unroll
    for (int j = 0; j < 16; ++j) wgh_r[j] = wghp[((kh16 + j) << 10) + (g << 8) + cc];
    #pragma unroll
    for (int j = 0; j < 8; ++j)  w1_r[j]  = w1p[(((g << 5) + kq8 + j) << 7) + ffi];
    #pragma unroll
    for (int j = 0; j < 8; ++j)  w2_r[j]  = w2p[(((g << 4) + fh8 + j) << 8) + cc];
    #pragma unroll
    for (int j = 0; j < 16; ++j) KEEPU4(wgh_r[j]);
    #pragma unroll
    for (int j = 0; j < 8; ++j)  KEEPU4(w1_r[j]);
    #pragma unroll
    for (int j = 0; j < 8; ++j)  KEEPU4(w2_r[j]);

    __syncthreads();

    for (int t0 = 0; t0 < T_STEPS; t0 += CHUNK) {
        // ---- stage x chunk: 2 batches x 16 steps x 256 dims = 2048 float4 ----
        #pragma unroll
        for (int j = 0; j < 4; ++j) {
            int i4 = j * 512 + tid;
            int bl = i4 >> 10, rem = i4 & 1023, tl = rem >> 6, d4 = rem & 63;
            float4 v = reinterpret_cast<const float4*>(
                x + ((size_t)(t0 + tl) * BATCH + bp + (bl << 6)) * DIM)[d4];
            int base = bl * 4096 + tl * 256 + (d4 << 2);
            xc[base + 0] = (_Float16)v.x;
            xc[base + 1] = (_Float16)v.y;
            xc[base + 2] = (_Float16)v.z;
            xc[base + 3] = (_Float16)v.w;
        }
        __syncthreads();

        // ---- chunk x-GEMM (streams Wgx slice once/chunk = ~8KB/step amortized) ----
        {
            const int th = tid >> 8;                       // tc block 0/1 -> tc = th*8+j
            const U4H* xcv = reinterpret_cast<const U4H*>(xc);   // [2][16][32]
            float acc[2][8];
            #pragma unroll
            for (int bl = 0; bl < 2; ++bl)
                #pragma unroll
                for (int j = 0; j < 8; ++j) acc[bl][j] = bgs[cc];
            for (int k8 = 0; k8 < 32; ++k8) {
                U4H w; w.u = wgxp[(k8 << 10) + (g << 8) + cc];
                #pragma unroll
                for (int bl = 0; bl < 2; ++bl) {
                    #pragma unroll
                    for (int j = 0; j < 8; ++j) {
                        U4H xv; xv.u = xcv[bl * 512 + (th * 8 + j) * 32 + k8].u;
                        acc[bl][j] = fdot2_(xv.h[0], w.h[0], acc[bl][j]);
                        acc[bl][j] = fdot2_(xv.h[1], w.h[1], acc[bl][j]);
                        acc[bl][j] = fdot2_(xv.h[2], w.h[2], acc[bl][j]);
                        acc[bl][j] = fdot2_(xv.h[3], w.h[3], acc[bl][j]);
                    }
                }
            }
            #pragma unroll
            for (int bl = 0; bl < 2; ++bl)
                #pragma unroll
                for (int j = 0; j < 8; ++j)
                    zxc[bl * 4096 + (th * 8 + j) * 256 + cc] = (_Float16)acc[bl][j];
        }
        __syncthreads();

        for (int tc = 0; tc < CHUNK; ++tc) {
            const int s = t0 + tc;

            // ---- p1: z partials from register Wgh; h via uniform b128 LDS reads ----
            {
                const uint4* hA4 = reinterpret_cast<const uint4*>(ch2buf);
                const uint4* hB4 = reinterpret_cast<const uint4*>(ch2buf + 256);
                float aA = 0.0f, aB = 0.0f;
                #pragma unroll
                for (int j = 0; j < 16; ++j) {
                    const int k8 = kh16 + j;
                    U4H w;  w.u  = wgh_r[j];
                    U4H ha; ha.u = hA4[k8];
                    U4H hb; hb.u = hB4[k8];
                    aA = fdot2_(ha.h[0], w.h[0], aA);
                    aA = fdot2_(ha.h[1], w.h[1], aA);
                    aA = fdot2_(ha.h[2], w.h[2], aA);
                    aA = fdot2_(ha.h[3], w.h[3], aA);
                    aB = fdot2_(hb.h[0], w.h[0], aB);
                    aB = fdot2_(hb.h[1], w.h[1], aB);
                    aB = fdot2_(hb.h[2], w.h[2], aB);
                    aB = fdot2_(hb.h[3], w.h[3], aB);
                }
                pbuf[tid] = aA;
                pbuf[512 + tid] = aB;
            }
            __syncthreads();
            {   // combine1: z = zx + partials; (bl,c) = tid
                const int bl = tid >> 8, c = tid & 255;
                float z = (float)zxc[bl * 4096 + tc * 256 + c]
                        + pbuf[bl * 512 + c] + pbuf[bl * 512 + 256 + c];
                zh[bl * 256 + c] = (_Float16)z;
            }
            __syncthreads();

            // ---- p2: h1 partials from register W1 ----
            {
                const uint4* zA4 = reinterpret_cast<const uint4*>(zh);
                const uint4* zB4 = reinterpret_cast<const uint4*>(zh + 256);
                float aA = 0.0f, aB = 0.0f;
                #pragma unroll
                for (int j = 0; j < 8; ++j) {
                    const int k8 = kq8 + j;
                    U4H w;  w.u  = w1_r[j];
                    U4H za; za.u = zA4[k8];
                    U4H zb; zb.u = zB4[k8];
                    aA = fdot2_(za.h[0], w.h[0], aA);
                    aA = fdot2_(za.h[1], w.h[1], aA);
                    aA = fdot2_(za.h[2], w.h[2], aA);
                    aA = fdot2_(za.h[3], w.h[3], aA);
                    aB = fdot2_(zb.h[0], w.h[0], aB);
                    aB = fdot2_(zb.h[1], w.h[1], aB);
                    aB = fdot2_(zb.h[2], w.h[2], aB);
                    aB = fdot2_(zb.h[3], w.h[3], aB);
                }
                pbuf[tid] = aA;
                pbuf[512 + tid] = aB;
            }
            __syncthreads();
            if (tid < 256) {   // combine2: (bl,f)
                const int bl = tid >> 7, f = tid & 127;
                float v = b1s[f] + pbuf[bl * 512 + f] + pbuf[bl * 512 + 128 + f]
                                 + pbuf[bl * 512 + 256 + f] + pbuf[bl * 512 + 384 + f];
                h1h[bl * 128 + f] = (_Float16)fmaxf(v, 0.0f);
            }
            __syncthreads();

            // ---- p3: z2 partials from register W2 ----
            {
                const uint4* pA4 = reinterpret_cast<const uint4*>(h1h);
                const uint4* pB4 = reinterpret_cast<const uint4*>(h1h + 128);
                float aA = 0.0f, aB = 0.0f;
                #pragma unroll
                for (int j = 0; j < 8; ++j) {
                    const int f8 = fh8 + j;
                    U4H w;  w.u  = w2_r[j];
                    U4H ha; ha.u = pA4[f8];
                    U4H hb; hb.u = pB4[f8];
                    aA = fdot2_(ha.h[0], w.h[0], aA);
                    aA = fdot2_(ha.h[1], w.h[1], aA);
                    aA = fdot2_(ha.h[2], w.h[2], aA);
                    aA = fdot2_(ha.h[3], w.h[3], aA);
                    aB = fdot2_(hb.h[0], w.h[0], aB);
                    aB = fdot2_(hb.h[1], w.h[1], aB);
                    aB = fdot2_(hb.h[2], w.h[2], aB);
                    aB = fdot2_(hb.h[3], w.h[3], aB);
                }
                pbuf[tid] = aA;
                pbuf[512 + tid] = aB;
            }
            __syncthreads();

            // ---- combine3 + publish (tag s+1) + spin on 4 gates + update ----
            {
                const int bl = tid >> 8, c = tid & 255;
                const int b  = bp + (bl << 6);
                float z2 = b2s[c] + pbuf[bl * 512 + c] + pbuf[bl * 512 + 256 + c];
                HU hu; hu.h = (_Float16)z2;
                unsigned word = ((unsigned)(s + 1) << 16) | (unsigned)hu.u;
                unsigned widx = (unsigned)(b * 2048 + g * 512 + ((s & 1) << 8) + c);
                __hip_atomic_store(&ex[widx], word, __ATOMIC_RELAXED, __HIP_MEMORY_SCOPE_AGENT);

                const unsigned base = (unsigned)(b * 2048 + ((s & 1) << 8) + c);
                const unsigned want = (unsigned)(s + 1) << 16;
                unsigned w0, w1, w2, w3;
                for (;;) {
                    w0 = __hip_atomic_load(&ex[base],        __ATOMIC_RELAXED, __HIP_MEMORY_SCOPE_AGENT);
                    w1 = __hip_atomic_load(&ex[base + 512],  __ATOMIC_RELAXED, __HIP_MEMORY_SCOPE_AGENT);
                    w2 = __hip_atomic_load(&ex[base + 1024], __ATOMIC_RELAXED, __HIP_MEMORY_SCOPE_AGENT);
                    w3 = __hip_atomic_load(&ex[base + 1536], __ATOMIC_RELAXED, __HIP_MEMORY_SCOPE_AGENT);
                    unsigned m = ((w0 ^ want) | (w1 ^ want) | (w2 ^ want) | (w3 ^ want)) & 0xFFFF0000u;
                    if (m == 0u) break;
                    __builtin_amdgcn_s_sleep(1);
                }
                HU hf, hi, hg, ho;
                hf.u = (unsigned short)(w0 & 0xFFFFu);
                hi.u = (unsigned short)(w1 & 0xFFFFu);
                hg.u = (unsigned short)(w2 & 0xFFFFu);
                ho.u = (unsigned short)(w3 & 0xFFFFu);
                float fg = sigmoidf_((float)hf.h);
                float ig = sigmoidf_((float)hi.h);
                float gg = tanhf_((float)hg.h);
                float og = sigmoidf_((float)ho.h);
                c_reg = fmaf(fg, c_reg, ig * gg);
                float hh = og * tanhf_(c_reg);
                ch2buf[bl * 256 + c] = (_Float16)hh;
                if (g == 0) {
                    out[((size_t)s * BATCH + b) * HID + c] = hh;
                    if (s == T_STEPS - 1) {
                        const size_t TBH = (size_t)T_STEPS * BATCH * HID;
                        out[TBH + (size_t)b * HID + c] = hh;
                        out[TBH + (size_t)BATCH * HID + (size_t)b * HID + c] = c_reg;
                    }
                }
            }
            __syncthreads();
        }
    }
}

// ---------------- fallback: R4 chunk kernel (one WG per batch element) ----------------
__global__ __launch_bounds__(1024)
void qlstm_chunk_kernel(const float* __restrict__ x,
                        const _Float16* __restrict__ ws,
                        const float* __restrict__ bg,
                        const float* __restrict__ b1,
                        const float* __restrict__ b2,
                        float* __restrict__ out)
{
    const int b   = blockIdx.x;
    const int tid = threadIdx.x;

    __shared__ __align__(16) _Float16 xc[CHUNK * DIM];
    __shared__ __align__(16) _Float16 zxc[CHUNK * 1024];
    __shared__ __align__(16) _Float16 zh[1024];
    __shared__ __align__(16) _Float16 h1h[512];
    __shared__ __align__(16) _Float16 ch2buf[HID];
    __shared__ float z2buf[1024];
    __shared__ float cbuf[HID];
    __shared__ float hbuf[HID];

    const float rbg = bg[tid];
    const float rb1 = (tid < 512) ? b1[tid] : 0.0f;
    const float rb2 = b2[tid];

    if (tid < HID) { cbuf[tid] = 0.0f; hbuf[tid] = 0.0f; ch2buf[tid] = (_Float16)0.0f; }

    const uint4* __restrict__ wgxp = reinterpret_cast<const uint4*>(ws + WGXP_OFF);
    const uint4* __restrict__ wghp = reinterpret_cast<const uint4*>(ws + WGHP_OFF);
    const uint4* __restrict__ w1p  = reinterpret_cast<const uint4*>(ws + W1P_OFF);
    const uint4* __restrict__ w2p  = reinterpret_cast<const uint4*>(ws + W2P_OFF);
    const h2* ch2 = reinterpret_cast<const h2*>(ch2buf);
    const U4H* xcv = reinterpret_cast<const U4H*>(xc);

    for (int t0 = 0; t0 < T_STEPS; t0 += CHUNK) {
        #pragma unroll
        for (int j = 0; j < (CHUNK * DIM) / 1024; ++j) {
            int idx = tid + j * 1024;
            int tl = idx >> 8, d = idx & 255;
            xc[tl * DIM + d] = (_Float16)x[((size_t)(t0 + tl) * BATCH + b) * DIM + d];
        }
        __syncthreads();

        {
            float acc[CHUNK];
            #pragma unroll
            for (int tc = 0; tc < CHUNK; ++tc) acc[tc] = rbg;
            for (int k8 = 0; k8 < DIM / 8; ++k8) {
                U4H w; w.u = wgxp[(k8 << 10) + tid];
                #pragma unroll
                for (int tc = 0; tc < CHUNK; ++tc) {
                    U4H xv; xv.u = xcv[tc * (DIM / 8) + k8].u;
                    acc[tc] = fdot2_(xv.h[0], w.h[0], acc[tc]);
                    acc[tc] = fdot2_(xv.h[1], w.h[1], acc[tc]);
                    acc[tc] = fdot2_(xv.h[2], w.h[2], acc[tc]);
                    acc[tc] = fdot2_(xv.h[3], w.h[3], acc[tc]);
                }
            }
            #pragma unroll
            for (int tc = 0; tc < CHUNK; ++tc) zxc[tc * 1024 + tid] = (_Float16)acc[tc];
        }
        __syncthreads();

        for (int tc = 0; tc < CHUNK; ++tc) {
            {
                float acc = (float)zxc[tc * 1024 + tid];
                #pragma unroll 8
                for (int k8 = 0; k8 < HID / 8; ++k8) {
                    U4H w; w.u = wghp[(k8 << 10) + tid];
                    acc = fdot2_(ch2[4 * k8 + 0], w.h[0], acc);
                    acc = fdot2_(ch2[4 * k8 + 1], w.h[1], acc);
                    acc = fdot2_(ch2[4 * k8 + 2], w.h[2], acc);
                    acc = fdot2_(ch2[4 * k8 + 3], w.h[3], acc);
                }
                zh[tid] = (_Float16)acc;
            }
            __syncthreads();

            if (tid < 512) {
                const int g = tid >> 7, f = tid & 127;
                const h2* zp = reinterpret_cast<const h2*>(zh + (g << 8));
                float acc = rb1;
                #pragma unroll 8
                for (int k8 = 0; k8 < HID / 8; ++k8) {
                    U4H w; w.u = w1p[(((g << 5) + k8) << 7) + f];
                    acc = fdot2_(zp[4 * k8 + 0], w.h[0], acc);
                    acc = fdot2_(zp[4 * k8 + 1], w.h[1], acc);
                    acc = fdot2_(zp[4 * k8 + 2], w.h[2], acc);
                    acc = fdot2_(zp[4 * k8 + 3], w.h[3], acc);
                }
                h1h[tid] = (_Float16)fmaxf(acc, 0.0f);
            }
            __syncthreads();

            {
                const int g = tid >> 8, hcol = tid & 255;
                const h2* hp = reinterpret_cast<const h2*>(h1h + (g << 7));
                float acc = rb2;
                #pragma unroll 8
                for (int f8 = 0; f8 < FF / 8; ++f8) {
                    U4H w; w.u = w2p[(((g << 4) + f8) << 8) + hcol];
                    acc = fdot2_(hp[4 * f8 + 0], w.h[0], acc);
                    acc = fdot2_(hp[4 * f8 + 1], w.h[1], acc);
                    acc = fdot2_(hp[4 * f8 + 2], w.h[2], acc);
                    acc = fdot2_(hp[4 * f8 + 3], w.h[3], acc);
                }
                z2buf[tid] = acc;
            }
            __syncthreads();

            if (tid < HID) {
                float zf = z2buf[tid];
                float zi = z2buf[HID + tid];
                float zg = z2buf[2 * HID + tid];
                float zo = z2buf[3 * HID + tid];
                float fg = sigmoidf_(zf);
                float ig = sigmoidf_(zi);
                float gg = tanhf_(zg);
                float og = sigmoidf_(zo);
                float cc = fmaf(fg, cbuf[tid], ig * gg);
                float hh = og * tanhf_(cc);
                cbuf[tid] = cc;
                hbuf[tid] = hh;
                ch2buf[tid] = (_Float16)hh;
                out[((size_t)(t0 + tc) * BATCH + b) * HID + tid] = hh;
            }
            __syncthreads();
        }
    }

    if (tid < HID) {
        const size_t TBH = (size_t)T_STEPS * BATCH * HID;
        out[TBH + (size_t)b * HID + tid] = hbuf[tid];
        out[TBH + (size_t)BATCH * HID + (size_t)b * HID + tid] = cbuf[tid];
    }
}

extern "C" void kernel_launch(void* const* d_in, const int* in_sizes, int n_in,
                              void* d_out, int out_size, void* d_ws, size_t ws_size,
                              hipStream_t stream) {
    const float* x  = (const float*)d_in[0];
    const float* Wg = (const float*)d_in[1];
    const float* bg = (const float*)d_in[2];
    const float* W1 = (const float*)d_in[3];
    const float* b1 = (const float*)d_in[4];
    const float* W2 = (const float*)d_in[5];
    const float* b2 = (const float*)d_in[6];
    float* out = (float*)d_out;
    char* wsc = (char*)d_ws;

    if (ws_size >= (size_t)WS_SPLIT4_BYTES) {
        _Float16* ws = (_Float16*)wsc;
        unsigned* ex = (unsigned*)(wsc + EX_BYTE_OFF);
        convert_kernel<<<WS_HALFS / 256, 256, 0, stream>>>(Wg, W1, W2, ws);
        exinit_kernel<<<EX_WORDS / 512, 512, 0, stream>>>(ex);
        qlstm_split4r_kernel<<<256, 512, 0, stream>>>(x, ws, ex, bg, b1, b2, out);
    } else if (ws_size >= (size_t)WS_HALFS * sizeof(_Float16)) {
        _Float16* ws = (_Float16*)wsc;
        convert_kernel<<<WS_HALFS / 256, 256, 0, stream>>>(Wg, W1, W2, ws);
        qlstm_chunk_kernel<<<BATCH, 1024, 0, stream>>>(x, ws, bg, b1, b2, out);
    }
}